// Round 1
// baseline (491.865 us; speedup 1.0000x reference)
//
#include <hip/hip_runtime.h>
#include <hip/hip_bf16.h>

// LightAttention: Z = softmax_n(Q/d4) @ [ softmax_n(K/d4)^T @ V ]
// Folded form: E=exp(Q/d4), F=exp(K/d4), Sq/Sk = column sums over n,
//   C[d,e] = (sum_n F[n,d] V[n,e]) / (Sq[d]*Sk[d]),  Z = E @ C.
// All GEMMs bf16 MFMA 16x16x32, 128x128 tiles, BK=32.
// LDS layout "chunk-major": slot = k8*128 + row (16B per slot) so that
// global_load_lds (lane*16B contiguous) and ds_read_b128 frag reads agree.

typedef __bf16 bf16_t;
typedef __attribute__((ext_vector_type(8))) __bf16 bf16x8;
typedef __attribute__((ext_vector_type(4))) float f32x4;

#define MFMA_BF16 __builtin_amdgcn_mfma_f32_16x16x32_bf16

__device__ inline void async_ld16(const void* g, void* l) {
  __builtin_amdgcn_global_load_lds(
      (const __attribute__((address_space(1))) void*)g,
      (__attribute__((address_space(3))) void*)l, 16, 0, 0);
}

#define INV_D4 0.2102241038134287f  // 1 / 512^0.25

// ---------------- W transpose+convert: W[in][out] f32 -> Wt[out][in] bf16 ----
__global__ __launch_bounds__(256) void wt_kernel(
    const float* __restrict__ Wq, const float* __restrict__ Wk,
    const float* __restrict__ Wv, bf16_t* __restrict__ Wt) {
  const int z = blockIdx.z;
  const float* W = (z == 0) ? Wq : (z == 1) ? Wk : Wv;
  bf16_t* O = Wt + (size_t)z * 262144;
  __shared__ __align__(16) bf16_t tile[64 * 72];
  const int t = threadIdx.x;
  const int r = t >> 2;
  const int c4 = (t & 3) * 16;
  const int in0 = blockIdx.x * 64, out0 = blockIdx.y * 64;
  const float* src = W + (size_t)(in0 + r) * 512 + out0 + c4;
#pragma unroll
  for (int i = 0; i < 4; ++i) {
    float4 f = ((const float4*)src)[i];
    tile[(c4 + i * 4 + 0) * 72 + r] = (__bf16)f.x;
    tile[(c4 + i * 4 + 1) * 72 + r] = (__bf16)f.y;
    tile[(c4 + i * 4 + 2) * 72 + r] = (__bf16)f.z;
    tile[(c4 + i * 4 + 3) * 72 + r] = (__bf16)f.w;
  }
  __syncthreads();
  bf16x8* dst = (bf16x8*)(O + (size_t)(out0 + r) * 512 + in0 + c4);
  const bf16x8* s = (const bf16x8*)(tile + r * 72 + c4);
  dst[0] = s[0];
  dst[1] = s[1];
}

// ---------------- Projection GEMM: X[32768x512]f32 @ Wt^T + b -> exp / plain bf16
__global__ __launch_bounds__(256, 2) void proj_kernel(
    const float* __restrict__ xq, const float* __restrict__ xk,
    const float* __restrict__ xv, const bf16_t* __restrict__ Wt,
    const float* __restrict__ bq, const float* __restrict__ bk,
    const float* __restrict__ bv, bf16_t* __restrict__ Eq,
    bf16_t* __restrict__ Fk, bf16_t* __restrict__ Vb) {
  const int z = blockIdx.z;
  const float* X = (z == 0) ? xq : (z == 1) ? xk : xv;
  const float* bias = (z == 0) ? bq : (z == 1) ? bk : bv;
  const bf16_t* W = Wt + (size_t)z * 262144;
  bf16_t* Out = (z == 0) ? Eq : (z == 1) ? Fk : Vb;
  const bool expmode = (z < 2);

  __shared__ __align__(16) bf16_t As[4096];
  __shared__ __align__(16) bf16_t Bs[4096];

  const int t = threadIdx.x;
  const int lane = t & 63, w = t >> 6;
  const int quad = lane >> 4, l15 = lane & 15;
  const int m0 = blockIdx.x * 128;
  const int n0 = blockIdx.y * 128;
  const int m_off = (w & 1) * 64, n_off = (w >> 1) * 64;

  f32x4 acc[4][4];
  const f32x4 zero4 = {0.f, 0.f, 0.f, 0.f};
#pragma unroll
  for (int i = 0; i < 4; ++i)
#pragma unroll
    for (int j = 0; j < 4; ++j) acc[i][j] = zero4;

  const int ar = t >> 1;
  const int ac = (t & 1) * 16;  // 0 or 16

  for (int ks = 0; ks < 16; ++ks) {
    const int k0 = ks * 32;
    // B tile: Wt rows n0..n0+127, k-slice, async direct to LDS (chunk-major)
#pragma unroll
    for (int i = 0; i < 2; ++i) {
      const int j = w * 2 + i;
      const int k8 = j >> 1;
      const int r = ((j & 1) << 6) + lane;
      async_ld16(W + (size_t)(n0 + r) * 512 + k0 + k8 * 8, Bs + j * 512);
    }
    // A tile: fp32 -> bf16 via VGPR (2 threads/row, 16 floats each)
    const float* arow = X + (size_t)(m0 + ar) * 512 + k0 + ac;
    float4 f0 = ((const float4*)arow)[0];
    float4 f1 = ((const float4*)arow)[1];
    float4 f2 = ((const float4*)arow)[2];
    float4 f3 = ((const float4*)arow)[3];
    bf16x8 p0, p1;
    p0[0] = (__bf16)f0.x; p0[1] = (__bf16)f0.y; p0[2] = (__bf16)f0.z; p0[3] = (__bf16)f0.w;
    p0[4] = (__bf16)f1.x; p0[5] = (__bf16)f1.y; p0[6] = (__bf16)f1.z; p0[7] = (__bf16)f1.w;
    p1[0] = (__bf16)f2.x; p1[1] = (__bf16)f2.y; p1[2] = (__bf16)f2.z; p1[3] = (__bf16)f2.w;
    p1[4] = (__bf16)f3.x; p1[5] = (__bf16)f3.y; p1[6] = (__bf16)f3.z; p1[7] = (__bf16)f3.w;
    ((bf16x8*)As)[(ac >> 3) * 128 + ar] = p0;
    ((bf16x8*)As)[((ac >> 3) + 1) * 128 + ar] = p1;

    __syncthreads();
    bf16x8 af[4], bfr[4];
#pragma unroll
    for (int mi = 0; mi < 4; ++mi)
      af[mi] = ((const bf16x8*)As)[quad * 128 + m_off + mi * 16 + l15];
#pragma unroll
    for (int ni = 0; ni < 4; ++ni)
      bfr[ni] = ((const bf16x8*)Bs)[quad * 128 + n_off + ni * 16 + l15];
#pragma unroll
    for (int mi = 0; mi < 4; ++mi)
#pragma unroll
      for (int ni = 0; ni < 4; ++ni)
        acc[mi][ni] = MFMA_BF16(af[mi], bfr[ni], acc[mi][ni], 0, 0, 0);
    __syncthreads();
  }

#pragma unroll
  for (int ni = 0; ni < 4; ++ni) {
    const int col = n0 + n_off + ni * 16 + l15;
    const float bv_ = bias[col];
#pragma unroll
    for (int mi = 0; mi < 4; ++mi) {
#pragma unroll
      for (int r = 0; r < 4; ++r) {
        const int row = m0 + m_off + mi * 16 + quad * 4 + r;
        float v = acc[mi][ni][r] + bv_;
        if (expmode) v = __expf(v * INV_D4);
        Out[(size_t)row * 512 + col] = (bf16_t)v;
      }
    }
  }
}

// ---------------- column sums over n: S[b,d] = sum_n E[b,n,d] ---------------
__global__ __launch_bounds__(256) void colsum_kernel(
    const bf16_t* __restrict__ Eq, const bf16_t* __restrict__ Fk,
    float* __restrict__ Sq, float* __restrict__ Sk) {
  const int b = blockIdx.x;
  const int c = blockIdx.y;
  const bf16_t* src = (blockIdx.z == 0) ? Eq : Fk;
  float* S = (blockIdx.z == 0) ? Sq : Sk;
  const int t = threadIdx.x;
  float s0 = 0.f, s1 = 0.f;
  const size_t base = ((size_t)b * 4096 + (size_t)c * 512) * 512;
  for (int r = 0; r < 512; ++r) {
    s0 += (float)src[base + (size_t)r * 512 + t];
    s1 += (float)src[base + (size_t)r * 512 + t + 256];
  }
  atomicAdd(&S[b * 512 + t], s0);
  atomicAdd(&S[b * 512 + t + 256], s1);
}

// ---------------- Bm GEMM: Bm[b,d,e] += sum_n F[b,n,d] * V[b,n,e] -----------
// Both operands need an LDS transpose during staging (padded rows, stride 40).
__global__ __launch_bounds__(256, 2) void bm_gemm(
    const bf16_t* __restrict__ Fk, const bf16_t* __restrict__ Vb,
    float* __restrict__ Bm) {
  const int b = blockIdx.z >> 3;
  const int s = blockIdx.z & 7;
  const int d0 = blockIdx.x * 128;
  const int e0 = blockIdx.y * 128;
  const bf16_t* F = Fk + (size_t)b * 4096 * 512;
  const bf16_t* V = Vb + (size_t)b * 4096 * 512;
  float* outBm = Bm + (size_t)b * 262144;

  __shared__ __align__(16) bf16_t As[128 * 40];
  __shared__ __align__(16) bf16_t Bs[128 * 40];

  const int t = threadIdx.x;
  const int lane = t & 63, w = t >> 6;
  const int quad = lane >> 4, l15 = lane & 15;
  const int m_off = (w & 1) * 64, n_off = (w >> 1) * 64;

  f32x4 acc[4][4];
  const f32x4 zero4 = {0.f, 0.f, 0.f, 0.f};
#pragma unroll
  for (int i = 0; i < 4; ++i)
#pragma unroll
    for (int j = 0; j < 4; ++j) acc[i][j] = zero4;

  for (int ks = 0; ks < 16; ++ks) {
    const int kn = s * 512 + ks * 32;
#pragma unroll
    for (int h = 0; h < 2; ++h) {
      const int c = t + h * 256;
      const int k = c >> 4;
      const int c8 = c & 15;
      bf16x8 fa = *(const bf16x8*)(F + (size_t)(kn + k) * 512 + d0 + c8 * 8);
      bf16x8 vv = *(const bf16x8*)(V + (size_t)(kn + k) * 512 + e0 + c8 * 8);
#pragma unroll
      for (int j = 0; j < 8; ++j) {
        const int jj = (j + c8) & 7;  // rotate to break bank collisions
        As[(c8 * 8 + jj) * 40 + k] = fa[jj];
        Bs[(c8 * 8 + jj) * 40 + k] = vv[jj];
      }
    }
    __syncthreads();
    bf16x8 af[4], bfr[4];
#pragma unroll
    for (int mi = 0; mi < 4; ++mi)
      af[mi] = *(const bf16x8*)(As + (m_off + mi * 16 + l15) * 40 + quad * 8);
#pragma unroll
    for (int ni = 0; ni < 4; ++ni)
      bfr[ni] = *(const bf16x8*)(Bs + (n_off + ni * 16 + l15) * 40 + quad * 8);
#pragma unroll
    for (int mi = 0; mi < 4; ++mi)
#pragma unroll
      for (int ni = 0; ni < 4; ++ni)
        acc[mi][ni] = MFMA_BF16(af[mi], bfr[ni], acc[mi][ni], 0, 0, 0);
    __syncthreads();
  }

#pragma unroll
  for (int mi = 0; mi < 4; ++mi)
#pragma unroll
    for (int ni = 0; ni < 4; ++ni) {
      const int ecol = e0 + n_off + ni * 16 + l15;
#pragma unroll
      for (int r = 0; r < 4; ++r) {
        const int drow = d0 + m_off + mi * 16 + quad * 4 + r;
        atomicAdd(&outBm[(size_t)drow * 512 + ecol], acc[mi][ni][r]);
      }
    }
}

// ---------------- scale + transpose: Ct[b,e,d] = Bm[b,d,e]/(Sq*Sk) ----------
__global__ __launch_bounds__(256) void scale_kernel(
    const float* __restrict__ Bm, const float* __restrict__ Sq,
    const float* __restrict__ Sk, bf16_t* __restrict__ Ct) {
  const int b = blockIdx.z;
  const int d0 = blockIdx.x * 64, e0 = blockIdx.y * 64;
  __shared__ __align__(16) bf16_t tile[64 * 72];
  const int t = threadIdx.x;
  const int r = t >> 2;
  const int c4 = (t & 3) * 16;
  const int d = d0 + r;
  const float f = 1.0f / (Sq[b * 512 + d] * Sk[b * 512 + d]);
  const float* src = Bm + (size_t)b * 262144 + (size_t)d * 512 + e0 + c4;
#pragma unroll
  for (int i = 0; i < 4; ++i) {
    float4 v = ((const float4*)src)[i];
    tile[(c4 + i * 4 + 0) * 72 + r] = (__bf16)(v.x * f);
    tile[(c4 + i * 4 + 1) * 72 + r] = (__bf16)(v.y * f);
    tile[(c4 + i * 4 + 2) * 72 + r] = (__bf16)(v.z * f);
    tile[(c4 + i * 4 + 3) * 72 + r] = (__bf16)(v.w * f);
  }
  __syncthreads();
  bf16x8* dst = (bf16x8*)(Ct + (size_t)b * 262144 + (size_t)(e0 + r) * 512 + d0 + c4);
  const bf16x8* s = (const bf16x8*)(tile + r * 72 + c4);
  dst[0] = s[0];
  dst[1] = s[1];
}

// ---------------- Z GEMM: Z[row,e] = sum_d E[row,d] * Ct[b][e][d] -----------
__global__ __launch_bounds__(256, 2) void z_gemm(
    const bf16_t* __restrict__ Eq, const bf16_t* __restrict__ Ct,
    float* __restrict__ out) {
  __shared__ __align__(16) bf16_t As[4096];
  __shared__ __align__(16) bf16_t Bs[4096];

  const int t = threadIdx.x;
  const int lane = t & 63, w = t >> 6;
  const int quad = lane >> 4, l15 = lane & 15;
  const int m0 = blockIdx.x * 128;
  const int n0 = blockIdx.y * 128;
  const int batch = m0 >> 12;
  const bf16_t* Bt = Ct + (size_t)batch * 262144;
  const int m_off = (w & 1) * 64, n_off = (w >> 1) * 64;

  f32x4 acc[4][4];
  const f32x4 zero4 = {0.f, 0.f, 0.f, 0.f};
#pragma unroll
  for (int i = 0; i < 4; ++i)
#pragma unroll
    for (int j = 0; j < 4; ++j) acc[i][j] = zero4;

  for (int ks = 0; ks < 16; ++ks) {
    const int k0 = ks * 32;
#pragma unroll
    for (int i = 0; i < 2; ++i) {
      const int j = w * 2 + i;
      const int k8 = j >> 1;
      const int r = ((j & 1) << 6) + lane;
      async_ld16(Eq + (size_t)(m0 + r) * 512 + k0 + k8 * 8, As + j * 512);
      async_ld16(Bt + (size_t)(n0 + r) * 512 + k0 + k8 * 8, Bs + j * 512);
    }
    __syncthreads();
    bf16x8 af[4], bfr[4];
#pragma unroll
    for (int mi = 0; mi < 4; ++mi)
      af[mi] = ((const bf16x8*)As)[quad * 128 + m_off + mi * 16 + l15];
#pragma unroll
    for (int ni = 0; ni < 4; ++ni)
      bfr[ni] = ((const bf16x8*)Bs)[quad * 128 + n_off + ni * 16 + l15];
#pragma unroll
    for (int mi = 0; mi < 4; ++mi)
#pragma unroll
      for (int ni = 0; ni < 4; ++ni)
        acc[mi][ni] = MFMA_BF16(af[mi], bfr[ni], acc[mi][ni], 0, 0, 0);
    __syncthreads();
  }

#pragma unroll
  for (int mi = 0; mi < 4; ++mi)
#pragma unroll
    for (int ni = 0; ni < 4; ++ni) {
      const int col = n0 + n_off + ni * 16 + l15;
#pragma unroll
      for (int r = 0; r < 4; ++r) {
        const int row = m0 + m_off + mi * 16 + quad * 4 + r;
        out[(size_t)row * 512 + col] = acc[mi][ni][r];
      }
    }
}

extern "C" void kernel_launch(void* const* d_in, const int* in_sizes, int n_in,
                              void* d_out, int out_size, void* d_ws,
                              size_t ws_size, hipStream_t stream) {
  const float* xq = (const float*)d_in[0];
  const float* xk = (const float*)d_in[1];
  const float* xv = (const float*)d_in[2];
  const float* Wq = (const float*)d_in[3];
  const float* bq = (const float*)d_in[4];
  const float* Wk = (const float*)d_in[5];
  const float* bk = (const float*)d_in[6];
  const float* Wv = (const float*)d_in[7];
  const float* bv = (const float*)d_in[8];
  float* out = (float*)d_out;

  char* ws = (char*)d_ws;
  bf16_t* Eq = (bf16_t*)(ws + 0);           // 32768x512 bf16 = 33,554,432 B
  bf16_t* Fk = (bf16_t*)(ws + 33554432);
  bf16_t* Vb = (bf16_t*)(ws + 67108864);
  bf16_t* Wt = (bf16_t*)(ws + 100663296);   // 3x512x512 bf16
  float* Sq = (float*)(ws + 102236160);     // 8x512 f32
  float* Sk = (float*)(ws + 102252544);
  float* Bm = (float*)(ws + 102268928);     // 8x512x512 f32
  bf16_t* Ct = (bf16_t*)(ws + 110657536);   // 8x512x512 bf16

  // zero Sq, Sk, Bm (atomic accumulation targets) in one contiguous memset
  hipMemsetAsync(ws + 102236160, 0, 16384 + 16384 + 8388608, stream);

  wt_kernel<<<dim3(8, 8, 3), 256, 0, stream>>>(Wq, Wk, Wv, Wt);
  proj_kernel<<<dim3(256, 4, 3), 256, 0, stream>>>(xq, xk, xv, Wt, bq, bk, bv,
                                                   Eq, Fk, Vb);
  colsum_kernel<<<dim3(8, 8, 2), 256, 0, stream>>>(Eq, Fk, Sq, Sk);
  bm_gemm<<<dim3(4, 4, 64), 256, 0, stream>>>(Fk, Vb, Bm);
  scale_kernel<<<dim3(8, 8, 8), 256, 0, stream>>>(Bm, Sq, Sk, Ct);
  z_gemm<<<dim3(256, 4, 1), 256, 0, stream>>>(Eq, Ct, out);
}

// Round 2
// 439.274 us; speedup vs baseline: 1.1197x; 1.1197x over previous
//
#include <hip/hip_runtime.h>
#include <hip/hip_bf16.h>

// LightAttention: Z = softmax_n(Q/d4) @ [ softmax_n(K/d4)^T @ V ]
// Folded: E=exp(Q/d4), F=exp(K/d4), Sq/Sk col-sums over n,
//   Bm[d,e] = sum_n F[n,d] V[n,e];  Ct[e,d] = Bm[d,e]/(Sq[d]Sk[d]);  Z = E @ Ct^T.
// proj writes E normal (z_gemm A-operand) and F,V TRANSPOSED (Ft[d][n], Vt[e][n])
// so bm_gemm is a pure m97-style GEMM (global_load_lds both operands, no LDS
// transpose, no atomics; split-K=2 partial buffers reduced in scale_kernel).
// Column sums fused into proj epilogue (shuffle-reduce + sparse atomics).

typedef __bf16 bf16_t;
typedef __attribute__((ext_vector_type(8))) __bf16 bf16x8;
typedef __attribute__((ext_vector_type(4))) float f32x4;

#define MFMA_BF16 __builtin_amdgcn_mfma_f32_16x16x32_bf16

__device__ inline void async_ld16(const void* g, void* l) {
  __builtin_amdgcn_global_load_lds(
      (const __attribute__((address_space(1))) void*)g,
      (__attribute__((address_space(3))) void*)l, 16, 0, 0);
}

#define INV_D4 0.2102241038134287f  // 1 / 512^0.25

// ---------------- W transpose+convert: W[in][out] f32 -> Wt[out][in] bf16 ----
__global__ __launch_bounds__(256) void wt_kernel(
    const float* __restrict__ Wq, const float* __restrict__ Wk,
    const float* __restrict__ Wv, bf16_t* __restrict__ Wt) {
  const int z = blockIdx.z;
  const float* W = (z == 0) ? Wq : (z == 1) ? Wk : Wv;
  bf16_t* O = Wt + (size_t)z * 262144;
  __shared__ __align__(16) bf16_t tile[64 * 72];
  const int t = threadIdx.x;
  const int r = t >> 2;
  const int c4 = (t & 3) * 16;
  const int in0 = blockIdx.x * 64, out0 = blockIdx.y * 64;
  const float* src = W + (size_t)(in0 + r) * 512 + out0 + c4;
#pragma unroll
  for (int i = 0; i < 4; ++i) {
    float4 f = ((const float4*)src)[i];
    tile[(c4 + i * 4 + 0) * 72 + r] = (__bf16)f.x;
    tile[(c4 + i * 4 + 1) * 72 + r] = (__bf16)f.y;
    tile[(c4 + i * 4 + 2) * 72 + r] = (__bf16)f.z;
    tile[(c4 + i * 4 + 3) * 72 + r] = (__bf16)f.w;
  }
  __syncthreads();
  bf16x8* dst = (bf16x8*)(O + (size_t)(out0 + r) * 512 + in0 + c4);
  const bf16x8* s = (const bf16x8*)(tile + r * 72 + c4);
  dst[0] = s[0];
  dst[1] = s[1];
}

// ---------------- Projection GEMM + fused epilogues ------------------------
// z=0: Eq[n][d] = exp(Q/d4) normal layout + colsum -> Sq
// z=1: Ft[d][n] = exp(K/d4) transposed + colsum -> Sk
// z=2: Vt[e][n] = V transposed
__global__ __launch_bounds__(256, 2) void proj_kernel(
    const float* __restrict__ xq, const float* __restrict__ xk,
    const float* __restrict__ xv, const bf16_t* __restrict__ Wt,
    const float* __restrict__ bq, const float* __restrict__ bk,
    const float* __restrict__ bv, bf16_t* __restrict__ Eq,
    bf16_t* __restrict__ Ft, bf16_t* __restrict__ Vt,
    float* __restrict__ Sq, float* __restrict__ Sk) {
  const int z = blockIdx.z;
  const float* X = (z == 0) ? xq : (z == 1) ? xk : xv;
  const float* bias = (z == 0) ? bq : (z == 1) ? bk : bv;
  const bf16_t* W = Wt + (size_t)z * 262144;

  __shared__ __align__(16) union U {
    struct {
      bf16_t As[4096];
      bf16_t Bs[4096];
    } s;
    bf16_t T[128 * 136];  // epilogue transpose tile (z=1,2)
  } u;

  const int t = threadIdx.x;
  const int lane = t & 63, w = t >> 6;
  const int quad = lane >> 4, l15 = lane & 15;
  const int m0 = blockIdx.x * 128;
  const int n0 = blockIdx.y * 128;
  const int m_off = (w & 1) * 64, n_off = (w >> 1) * 64;

  f32x4 acc[4][4];
  const f32x4 zero4 = {0.f, 0.f, 0.f, 0.f};
#pragma unroll
  for (int i = 0; i < 4; ++i)
#pragma unroll
    for (int j = 0; j < 4; ++j) acc[i][j] = zero4;

  const int ar = t >> 1;
  const int ac = (t & 1) * 16;
  const float* abase = X + (size_t)(m0 + ar) * 512 + ac;

  // prologue: A(0) -> regs
  float4 f0 = ((const float4*)abase)[0];
  float4 f1 = ((const float4*)abase)[1];
  float4 f2 = ((const float4*)abase)[2];
  float4 f3 = ((const float4*)abase)[3];

  for (int ks = 0; ks < 16; ++ks) {
    // pack current A regs -> LDS (chunk-major)
    bf16x8 p0, p1;
    p0[0] = (__bf16)f0.x; p0[1] = (__bf16)f0.y; p0[2] = (__bf16)f0.z; p0[3] = (__bf16)f0.w;
    p0[4] = (__bf16)f1.x; p0[5] = (__bf16)f1.y; p0[6] = (__bf16)f1.z; p0[7] = (__bf16)f1.w;
    p1[0] = (__bf16)f2.x; p1[1] = (__bf16)f2.y; p1[2] = (__bf16)f2.z; p1[3] = (__bf16)f2.w;
    p1[4] = (__bf16)f3.x; p1[5] = (__bf16)f3.y; p1[6] = (__bf16)f3.z; p1[7] = (__bf16)f3.w;
    ((bf16x8*)u.s.As)[(ac >> 3) * 128 + ar] = p0;
    ((bf16x8*)u.s.As)[((ac >> 3) + 1) * 128 + ar] = p1;

    // B tile async -> LDS
#pragma unroll
    for (int i = 0; i < 2; ++i) {
      const int j = w * 2 + i;
      const int k8 = j >> 1;
      const int r = ((j & 1) << 6) + lane;
      async_ld16(W + (size_t)(n0 + r) * 512 + ks * 32 + k8 * 8, u.s.Bs + j * 512);
    }
    __syncthreads();

    bf16x8 af[4], bfr[4];
#pragma unroll
    for (int mi = 0; mi < 4; ++mi)
      af[mi] = ((const bf16x8*)u.s.As)[quad * 128 + m_off + mi * 16 + l15];
#pragma unroll
    for (int ni = 0; ni < 4; ++ni)
      bfr[ni] = ((const bf16x8*)u.s.Bs)[quad * 128 + n_off + ni * 16 + l15];

    // prefetch next A chunk: drains at the loop-end barrier, under the MFMAs
    if (ks < 15) {
      const float4* p = (const float4*)(abase + (ks + 1) * 32);
      f0 = p[0]; f1 = p[1]; f2 = p[2]; f3 = p[3];
    }

#pragma unroll
    for (int mi = 0; mi < 4; ++mi)
#pragma unroll
      for (int ni = 0; ni < 4; ++ni)
        acc[mi][ni] = MFMA_BF16(af[mi], bfr[ni], acc[mi][ni], 0, 0, 0);
    __syncthreads();
  }

  const int b = m0 >> 12;
  if (z == 0) {
    float cs[4] = {0.f, 0.f, 0.f, 0.f};
#pragma unroll
    for (int ni = 0; ni < 4; ++ni) {
      const int col = n0 + n_off + ni * 16 + l15;
      const float bv_ = bias[col];
#pragma unroll
      for (int mi = 0; mi < 4; ++mi)
#pragma unroll
        for (int r = 0; r < 4; ++r) {
          const int row = m0 + m_off + mi * 16 + quad * 4 + r;
          float v = __expf((acc[mi][ni][r] + bv_) * INV_D4);
          Eq[(size_t)row * 512 + col] = (bf16_t)v;
          cs[ni] += v;
        }
    }
#pragma unroll
    for (int ni = 0; ni < 4; ++ni) {
      cs[ni] += __shfl_xor(cs[ni], 16);
      cs[ni] += __shfl_xor(cs[ni], 32);
    }
    if (lane < 16) {
#pragma unroll
      for (int ni = 0; ni < 4; ++ni)
        atomicAdd(&Sq[b * 512 + n0 + n_off + ni * 16 + lane], cs[ni]);
    }
  } else {
    // scatter into LDS transpose tile T[col][row], then coalesced store
    const bool expm = (z == 1);
    float cs[4] = {0.f, 0.f, 0.f, 0.f};
#pragma unroll
    for (int ni = 0; ni < 4; ++ni) {
      const int colc = n_off + ni * 16 + l15;
      const float bv_ = bias[n0 + colc];
#pragma unroll
      for (int mi = 0; mi < 4; ++mi)
#pragma unroll
        for (int r = 0; r < 4; ++r) {
          const int rowr = m_off + mi * 16 + quad * 4 + r;
          float v = acc[mi][ni][r] + bv_;
          if (expm) {
            v = __expf(v * INV_D4);
            cs[ni] += v;
          }
          u.T[colc * 136 + rowr] = (bf16_t)v;
        }
    }
    if (expm) {
#pragma unroll
      for (int ni = 0; ni < 4; ++ni) {
        cs[ni] += __shfl_xor(cs[ni], 16);
        cs[ni] += __shfl_xor(cs[ni], 32);
      }
      if (lane < 16) {
#pragma unroll
        for (int ni = 0; ni < 4; ++ni)
          atomicAdd(&Sk[b * 512 + n0 + n_off + ni * 16 + lane], cs[ni]);
      }
    }
    __syncthreads();
    bf16_t* Out = expm ? Ft : Vt;
    const int nloc = m0 & 4095;
    const int c = t >> 1;
    const int rh = (t & 1) * 64;
    bf16_t* dst = Out + (size_t)b * 2097152 + (size_t)(n0 + c) * 4096 + nloc + rh;
    const bf16_t* srcT = u.T + c * 136 + rh;
#pragma unroll
    for (int j = 0; j < 8; ++j) ((bf16x8*)dst)[j] = ((const bf16x8*)srcT)[j];
  }
}

// ---------------- Bm GEMM: Bmp[s][b][d][e] = sum_{n in slice} Ft[d][n]Vt[e][n]
__global__ __launch_bounds__(256, 2) void bm_gemm(
    const bf16_t* __restrict__ Ft, const bf16_t* __restrict__ Vt,
    float* __restrict__ Bmp) {
  const int b = blockIdx.z >> 1;
  const int s = blockIdx.z & 1;
  const int d0 = blockIdx.x * 128;
  const int e0 = blockIdx.y * 128;
  const bf16_t* A = Ft + (size_t)b * 2097152;
  const bf16_t* B = Vt + (size_t)b * 2097152;
  float* out = Bmp + ((size_t)s * 8 + b) * 262144;

  __shared__ __align__(16) bf16_t As[4096];
  __shared__ __align__(16) bf16_t Bs[4096];

  const int t = threadIdx.x;
  const int lane = t & 63, w = t >> 6;
  const int quad = lane >> 4, l15 = lane & 15;
  const int m_off = (w & 1) * 64, n_off = (w >> 1) * 64;

  f32x4 acc[4][4];
  const f32x4 zero4 = {0.f, 0.f, 0.f, 0.f};
#pragma unroll
  for (int i = 0; i < 4; ++i)
#pragma unroll
    for (int j = 0; j < 4; ++j) acc[i][j] = zero4;

  for (int ks = 0; ks < 64; ++ks) {
    const int k0 = s * 2048 + ks * 32;
#pragma unroll
    for (int i = 0; i < 2; ++i) {
      const int j = w * 2 + i;
      const int k8 = j >> 1;
      const int r = ((j & 1) << 6) + lane;
      async_ld16(A + (size_t)(d0 + r) * 4096 + k0 + k8 * 8, As + j * 512);
      async_ld16(B + (size_t)(e0 + r) * 4096 + k0 + k8 * 8, Bs + j * 512);
    }
    __syncthreads();
    bf16x8 af[4], bfr[4];
#pragma unroll
    for (int mi = 0; mi < 4; ++mi)
      af[mi] = ((const bf16x8*)As)[quad * 128 + m_off + mi * 16 + l15];
#pragma unroll
    for (int ni = 0; ni < 4; ++ni)
      bfr[ni] = ((const bf16x8*)Bs)[quad * 128 + n_off + ni * 16 + l15];
#pragma unroll
    for (int mi = 0; mi < 4; ++mi)
#pragma unroll
      for (int ni = 0; ni < 4; ++ni)
        acc[mi][ni] = MFMA_BF16(af[mi], bfr[ni], acc[mi][ni], 0, 0, 0);
    __syncthreads();
  }

#pragma unroll
  for (int mi = 0; mi < 4; ++mi)
#pragma unroll
    for (int ni = 0; ni < 4; ++ni) {
      const int ecol = e0 + n_off + ni * 16 + l15;
#pragma unroll
      for (int r = 0; r < 4; ++r) {
        const int drow = d0 + m_off + mi * 16 + quad * 4 + r;
        out[(size_t)drow * 512 + ecol] = acc[mi][ni][r];
      }
    }
}

// ---------------- scale + reduce partials + transpose -----------------------
// Ct[b][e][d] = (Bmp0+Bmp1)[b][d][e] / (Sq[b][d]*Sk[b][d])
__global__ __launch_bounds__(256) void scale_kernel(
    const float* __restrict__ Bmp, const float* __restrict__ Sq,
    const float* __restrict__ Sk, bf16_t* __restrict__ Ct) {
  const int b = blockIdx.z;
  const int d0 = blockIdx.x * 64, e0 = blockIdx.y * 64;
  __shared__ __align__(16) bf16_t tile[64 * 72];
  const int t = threadIdx.x;
  const int r = t >> 2;
  const int c4 = (t & 3) * 16;
  const int d = d0 + r;
  const float f = 1.0f / (Sq[b * 512 + d] * Sk[b * 512 + d]);
  const float* p0 = Bmp + (size_t)b * 262144 + (size_t)d * 512 + e0 + c4;
  const float* p1 = p0 + 2097152;  // second split buffer (8*262144)
#pragma unroll
  for (int i = 0; i < 4; ++i) {
    float4 v0 = ((const float4*)p0)[i];
    float4 v1 = ((const float4*)p1)[i];
    tile[(c4 + i * 4 + 0) * 72 + r] = (__bf16)((v0.x + v1.x) * f);
    tile[(c4 + i * 4 + 1) * 72 + r] = (__bf16)((v0.y + v1.y) * f);
    tile[(c4 + i * 4 + 2) * 72 + r] = (__bf16)((v0.z + v1.z) * f);
    tile[(c4 + i * 4 + 3) * 72 + r] = (__bf16)((v0.w + v1.w) * f);
  }
  __syncthreads();
  bf16x8* dst = (bf16x8*)(Ct + (size_t)b * 262144 + (size_t)(e0 + r) * 512 + d0 + c4);
  const bf16x8* s = (const bf16x8*)(tile + r * 72 + c4);
  dst[0] = s[0];
  dst[1] = s[1];
}

// ---------------- Z GEMM: Z[row,e] = sum_d E[row,d] * Ct[b][e][d] -----------
__global__ __launch_bounds__(256, 2) void z_gemm(
    const bf16_t* __restrict__ Eq, const bf16_t* __restrict__ Ct,
    float* __restrict__ out) {
  __shared__ __align__(16) bf16_t As[4096];
  __shared__ __align__(16) bf16_t Bs[4096];

  const int t = threadIdx.x;
  const int lane = t & 63, w = t >> 6;
  const int quad = lane >> 4, l15 = lane & 15;
  const int m0 = blockIdx.x * 128;
  const int n0 = blockIdx.y * 128;
  const int batch = m0 >> 12;
  const bf16_t* Bt = Ct + (size_t)batch * 262144;
  const int m_off = (w & 1) * 64, n_off = (w >> 1) * 64;

  f32x4 acc[4][4];
  const f32x4 zero4 = {0.f, 0.f, 0.f, 0.f};
#pragma unroll
  for (int i = 0; i < 4; ++i)
#pragma unroll
    for (int j = 0; j < 4; ++j) acc[i][j] = zero4;

  for (int ks = 0; ks < 16; ++ks) {
    const int k0 = ks * 32;
#pragma unroll
    for (int i = 0; i < 2; ++i) {
      const int j = w * 2 + i;
      const int k8 = j >> 1;
      const int r = ((j & 1) << 6) + lane;
      async_ld16(Eq + (size_t)(m0 + r) * 512 + k0 + k8 * 8, As + j * 512);
      async_ld16(Bt + (size_t)(n0 + r) * 512 + k0 + k8 * 8, Bs + j * 512);
    }
    __syncthreads();
    bf16x8 af[4], bfr[4];
#pragma unroll
    for (int mi = 0; mi < 4; ++mi)
      af[mi] = ((const bf16x8*)As)[quad * 128 + m_off + mi * 16 + l15];
#pragma unroll
    for (int ni = 0; ni < 4; ++ni)
      bfr[ni] = ((const bf16x8*)Bs)[quad * 128 + n_off + ni * 16 + l15];
#pragma unroll
    for (int mi = 0; mi < 4; ++mi)
#pragma unroll
      for (int ni = 0; ni < 4; ++ni)
        acc[mi][ni] = MFMA_BF16(af[mi], bfr[ni], acc[mi][ni], 0, 0, 0);
    __syncthreads();
  }

#pragma unroll
  for (int mi = 0; mi < 4; ++mi)
#pragma unroll
    for (int ni = 0; ni < 4; ++ni) {
      const int col = n0 + n_off + ni * 16 + l15;
#pragma unroll
      for (int r = 0; r < 4; ++r) {
        const int row = m0 + m_off + mi * 16 + quad * 4 + r;
        out[(size_t)row * 512 + col] = acc[mi][ni][r];
      }
    }
}

extern "C" void kernel_launch(void* const* d_in, const int* in_sizes, int n_in,
                              void* d_out, int out_size, void* d_ws,
                              size_t ws_size, hipStream_t stream) {
  const float* xq = (const float*)d_in[0];
  const float* xk = (const float*)d_in[1];
  const float* xv = (const float*)d_in[2];
  const float* Wq = (const float*)d_in[3];
  const float* bq = (const float*)d_in[4];
  const float* Wk = (const float*)d_in[5];
  const float* bk = (const float*)d_in[6];
  const float* Wv = (const float*)d_in[7];
  const float* bv = (const float*)d_in[8];
  float* out = (float*)d_out;

  char* ws = (char*)d_ws;
  bf16_t* Eq = (bf16_t*)(ws + 0);           // 8x4096x512 bf16  33,554,432 B
  bf16_t* Ft = (bf16_t*)(ws + 33554432);    // 8x512x4096 bf16 (transposed F)
  bf16_t* Vt = (bf16_t*)(ws + 67108864);    // 8x512x4096 bf16 (transposed V)
  bf16_t* Wt = (bf16_t*)(ws + 100663296);   // 3x512x512 bf16
  float* Sq = (float*)(ws + 102236160);     // 8x512 f32
  float* Sk = (float*)(ws + 102252544);
  float* Bmp = (float*)(ws + 102268928);    // 2 x 8x512x512 f32 split-K partials
  bf16_t* Ct = (bf16_t*)(ws + 33554432);    // aliases Ft (dead after bm_gemm)

  // zero the colsum atomic targets only
  hipMemsetAsync(ws + 102236160, 0, 32768, stream);

  wt_kernel<<<dim3(8, 8, 3), 256, 0, stream>>>(Wq, Wk, Wv, Wt);
  proj_kernel<<<dim3(256, 4, 3), 256, 0, stream>>>(xq, xk, xv, Wt, bq, bk, bv,
                                                   Eq, Ft, Vt, Sq, Sk);
  bm_gemm<<<dim3(4, 4, 16), 256, 0, stream>>>(Ft, Vt, Bmp);
  scale_kernel<<<dim3(8, 8, 8), 256, 0, stream>>>(Bmp, Sq, Sk, Ct);
  z_gemm<<<dim3(256, 4, 1), 256, 0, stream>>>(Eq, Ct, out);
}